// Round 5
// baseline (3050.900 us; speedup 1.0000x reference)
//
#include <hip/hip_runtime.h>
#include <hip/hip_bf16.h>
#include <hip/hip_fp16.h>

using half4_t = __attribute__((ext_vector_type(4))) _Float16;
using half8_t = __attribute__((ext_vector_type(8))) _Float16;
using f32x4   = __attribute__((ext_vector_type(4))) float;

#define B_   64
#define T_   2048
#define D_   256
#define U_   256
#define NG   768
#define TC   512
#define NCHUNK (T_/TC)
#define NB   8
#define G_   8
#define PAGE_B 12288   // bytes per (g,t) xw page: 8*768*2

typedef const __attribute__((address_space(1))) void* gptr_t;
typedef __attribute__((address_space(3))) void* lptr_t;

__device__ __forceinline__ float rcpf(float x) { return __builtin_amdgcn_rcpf(x); }

// ---------------- conversions ----------------

__global__ void conv_x_chunk(const float* __restrict__ x, _Float16* __restrict__ xh, int t0) {
  size_t idx = ((size_t)blockIdx.x * 256 + threadIdx.x) * 8;
  int b   = (int)(idx >> 17);
  int rem = (int)(idx & 131071);
  const float4* p = (const float4*)(x + ((size_t)(b * T_ + t0)) * D_ + rem);
  float4 v0 = p[0], v1 = p[1];
  half8_t o;
  o[0] = (_Float16)v0.x; o[1] = (_Float16)v0.y; o[2] = (_Float16)v0.z; o[3] = (_Float16)v0.w;
  o[4] = (_Float16)v1.x; o[5] = (_Float16)v1.y; o[6] = (_Float16)v1.z; o[7] = (_Float16)v1.w;
  *(half8_t*)(xh + idx) = o;
}

// src [256][768] f32 -> dst [768][256] f16 (transpose + convert)
__global__ void conv_T(const float* __restrict__ src, _Float16* __restrict__ dst) {
  int idx = blockIdx.x * 256 + threadIdx.x;
  int d = idx / NG;
  int j = idx - d * NG;
  dst[j * 256 + d] = (_Float16)src[idx];
}

// ---------------- phase 1: xw = x @ kernel + bias -> scattered scan fragments ----------------
#define BM 128
#define BN 128

__global__ __launch_bounds__(256, 2) void gemm16(
    const _Float16* __restrict__ A,
    const _Float16* __restrict__ BT,
    const float* __restrict__ bias,
    _Float16* __restrict__ xwl)
{
  __shared__ alignas(16) _Float16 As[BM * 32];
  __shared__ alignas(16) _Float16 Bs[BN * 32];
  const int tid = threadIdx.x, l = tid & 63, w = tid >> 6;
  const int NT = NG / BN;
  const int mt = blockIdx.x / NT, nt = blockIdx.x % NT;
  const char* Ab = (const char*)A  + (size_t)mt * BM * 512;
  const char* Bb = (const char*)BT + (size_t)nt * BN * 512;
  const int wm = (w & 1) * 64, wn = (w >> 1) * 64;
  f32x4 acc[4][4] = {};

  for (int kt = 0; kt < 8; ++kt) {
    #pragma unroll
    for (int s = 0; s < 2; ++s) {
      int c = tid + s * 256;
      int row = c >> 2, gq = c & 3;
      int gs = gq ^ ((row >> 1) & 3);
      __builtin_amdgcn_global_load_lds(
        (gptr_t)(Ab + (size_t)row * 512 + kt * 64 + gs * 16),
        (lptr_t)((char*)As + c * 16), 16, 0, 0);
    }
    #pragma unroll
    for (int s = 0; s < 2; ++s) {
      int c = tid + s * 256;
      int row = c >> 2, gq = c & 3;
      int gs = gq ^ ((row >> 1) & 3);
      __builtin_amdgcn_global_load_lds(
        (gptr_t)(Bb + (size_t)row * 512 + kt * 64 + gs * 16),
        (lptr_t)((char*)Bs + c * 16), 16, 0, 0);
    }
    __syncthreads();

    half8_t av[4], bv[4];
    #pragma unroll
    for (int m = 0; m < 4; ++m) {
      int row = wm + m * 16 + (l & 15);
      int off = row * 64 + (((l >> 4) ^ ((row >> 1) & 3)) << 4);
      av[m] = *(const half8_t*)((const char*)As + off);
    }
    #pragma unroll
    for (int n = 0; n < 4; ++n) {
      int row = wn + n * 16 + (l & 15);
      int off = row * 64 + (((l >> 4) ^ ((row >> 1) & 3)) << 4);
      bv[n] = *(const half8_t*)((const char*)Bs + off);
    }
    #pragma unroll
    for (int m = 0; m < 4; ++m)
      #pragma unroll
      for (int n = 0; n < 4; ++n)
        acc[m][n] = __builtin_amdgcn_mfma_f32_16x16x32_f16(av[m], bv[n], acc[m][n], 0, 0, 0);
    __syncthreads();
  }

  // epilogue: scatter into scan fragment layout, bias added.
  int m0 = mt * BM, n0 = nt * BN;
  #pragma unroll
  for (int m = 0; m < 4; ++m) {
    #pragma unroll
    for (int n = 0; n < 4; ++n) {
      int c = n0 + wn + n * 16 + (l & 15);
      int gate = c >> 8, u = c & 255;
      int wv = u >> 5, tt2 = (u >> 4) & 1, hi2 = (u >> 2) & 3, q2 = u & 3;
      size_t coff = (size_t)wv * 768 + gate * 256 + tt2 * 128 + hi2 * 4 + q2;
      float bc = bias[c];
      #pragma unroll
      for (int q = 0; q < 4; ++q) {
        int arow = m0 + wm + m * 16 + ((l >> 4) * 4 + q);
        int b = arow >> 9, tloc = arow & 511;
        int gg = b >> 3, be2 = b & 7;
        xwl[(size_t)(gg * 512 + tloc) * 6144 + coff + be2 * 16] = (_Float16)(acc[m][n][q] + bc);
      }
    }
  }
}

// ---------------- phase 2: MFMA GRU scan, rec register-resident ----------------
#define DECLK(k) half8_t A0_##k, A1_##k, A2_##k, A3_##k, A4_##k, A5_##k;
#define LOADK(k) A0_##k = rp0[4*k]; A1_##k = rp1[4*k]; A2_##k = rp2[4*k]; \
                 A3_##k = rp3[4*k]; A4_##k = rp4[4*k]; A5_##k = rp5[4*k];
// Opaque pass-through: forbids rematerialization-by-reload, pins frags in VGPRs.
#define PINK(k) asm volatile("" : "+v"(A0_##k), "+v"(A1_##k), "+v"(A2_##k), \
                                  "+v"(A3_##k), "+v"(A4_##k), "+v"(A5_##k));
#define MSTEP(k) { half8_t Bf = *(const half8_t*)(hb + (bi << 9) + ((((k)*4 + hi) ^ (bi & 7)) << 4)); \
  a0 = __builtin_amdgcn_mfma_f32_16x16x32_f16(A0_##k, Bf, a0, 0, 0, 0); \
  a1 = __builtin_amdgcn_mfma_f32_16x16x32_f16(A1_##k, Bf, a1, 0, 0, 0); \
  a2 = __builtin_amdgcn_mfma_f32_16x16x32_f16(A2_##k, Bf, a2, 0, 0, 0); \
  a3 = __builtin_amdgcn_mfma_f32_16x16x32_f16(A3_##k, Bf, a3, 0, 0, 0); \
  a4 = __builtin_amdgcn_mfma_f32_16x16x32_f16(A4_##k, Bf, a4, 0, 0, 0); \
  a5 = __builtin_amdgcn_mfma_f32_16x16x32_f16(A5_##k, Bf, a5, 0, 0, 0); }

#define GSTEP(q, hrq) { \
      float sz = __shfl_up(a1[q], 8, 16); \
      float sr = __shfl_up(a3[q], 8, 16); \
      float sh = __shfl_up(a5[q], 8, 16); \
      float az = tte ? sz : a0[q]; \
      float ar = tte ? sr : a2[q]; \
      float ah = tte ? sh : a4[q]; \
      float zp  = az + (float)xz[q]; \
      float rp_ = ar + (float)xr[q]; \
      float hp_ = ah + (float)xh[q]; \
      float zz = rcpf(1.f + __expf(-zp)); \
      float rr = rcpf(1.f + __expf(-rp_)); \
      float y  = rr * (hp_ - hrq) + hrq; \
      float th = 2.f * rcpf(1.f + __expf(-2.f * y)) - 1.f; \
      hrq = zz * (hrq - th) + th; \
      hp[q] = (_Float16)hrq; ov[q] = hrq; }

__global__ __launch_bounds__(512, 1) void scan_mfma(
    const _Float16* __restrict__ xws,
    const _Float16* __restrict__ rT,     // [768][256] f16
    float* __restrict__ out,             // [64][2048][256] f32 (pre-LN h written here)
    float* __restrict__ hg,              // [64][256] f32
    int t0)
{
  const int g = blockIdx.x, tid = threadIdx.x;
  const int w = tid >> 6, l = tid & 63, bi = l & 15, hi = l >> 4;
  const int be = bi & 7, tte = bi >> 3;
  const int u0e = 32 * w + tte * 16 + hi * 4;

  __shared__ alignas(16) _Float16 Hsw[2][16 * 256];   // 2 x 8 KB, granule-swizzled

  { half8_t z8 = {};
    *(half8_t*)((char*)Hsw + tid * 16) = z8;
    *(half8_t*)((char*)Hsw + 8192 + tid * 16) = z8; }

  const half8_t* rp0 = (const half8_t*)(rT + (size_t)((2*w + 0)*16 + bi) * 256 + hi * 8);
  const half8_t* rp1 = (const half8_t*)(rT + (size_t)((2*w + 1)*16 + bi) * 256 + hi * 8);
  const half8_t* rp2 = (const half8_t*)(rT + (size_t)((16 + 2*w)*16 + bi) * 256 + hi * 8);
  const half8_t* rp3 = (const half8_t*)(rT + (size_t)((17 + 2*w)*16 + bi) * 256 + hi * 8);
  const half8_t* rp4 = (const half8_t*)(rT + (size_t)((32 + 2*w)*16 + bi) * 256 + hi * 8);
  const half8_t* rp5 = (const half8_t*)(rT + (size_t)((33 + 2*w)*16 + bi) * 256 + hi * 8);

  DECLK(0) DECLK(1) DECLK(2) DECLK(3) DECLK(4) DECLK(5) DECLK(6) DECLK(7)
  LOADK(0) LOADK(1) LOADK(2) LOADK(3) LOADK(4) LOADK(5) LOADK(6) LOADK(7)
  PINK(0) PINK(1) PINK(2) PINK(3) PINK(4) PINK(5) PINK(6) PINK(7)

  float hr0, hr1, hr2, hr3;
  if (t0 == 0) { hr0 = hr1 = hr2 = hr3 = 0.f; }
  else { f32x4 hv = *(const f32x4*)(hg + (size_t)(g * 8 + be) * 256 + u0e);
         hr0 = hv[0]; hr1 = hv[1]; hr2 = hv[2]; hr3 = hv[3]; }

  const int gran0 = 4 * w + 2 * tte + (hi >> 1);
  const int hwoff = (be << 9) + ((gran0 ^ be) << 4) + ((hi & 1) << 3);

  __syncthreads();   // zero-init done
  { half4_t hp0;
    hp0[0] = (_Float16)hr0; hp0[1] = (_Float16)hr1;
    hp0[2] = (_Float16)hr2; hp0[3] = (_Float16)hr3;
    *(half4_t*)((char*)Hsw + hwoff) = hp0; }

  const char* xp = (const char*)xws + (size_t)g * TC * PAGE_B
                 + ((w * 768 + be * 16 + hi * 4) << 1) + (tte << 8);
  half4_t xz = *(const half4_t*)(xp);
  half4_t xr = *(const half4_t*)(xp + 512);
  half4_t xh = *(const half4_t*)(xp + 1024);

  float* outp = out + ((size_t)(g * 8 + be) * T_ + t0) * U_ + u0e;

  __syncthreads();   // h0 visible

  for (int t = 0; t < TC; ++t) {
    const char* hb = (const char*)Hsw + ((t & 1) << 13);
    f32x4 a0 = {}, a1 = {}, a2 = {}, a3 = {}, a4 = {}, a5 = {};
    MSTEP(0) MSTEP(1) MSTEP(2) MSTEP(3) MSTEP(4) MSTEP(5) MSTEP(6) MSTEP(7)

    half4_t hp; f32x4 ov;
    GSTEP(0, hr0) GSTEP(1, hr1) GSTEP(2, hr2) GSTEP(3, hr3)

    *(half4_t*)((char*)Hsw + (((t & 1) ^ 1) << 13) + hwoff) = hp;
    *(f32x4*)outp = ov;
    outp += U_;

    if (t + 1 < TC) {
      xp += PAGE_B;
      xz = *(const half4_t*)(xp);
      xr = *(const half4_t*)(xp + 512);
      xh = *(const half4_t*)(xp + 1024);
    }
    __syncthreads();
  }

  { f32x4 hv; hv[0] = hr0; hv[1] = hr1; hv[2] = hr2; hv[3] = hr3;
    *(f32x4*)(hg + (size_t)(g * 8 + be) * 256 + u0e) = hv; }
}

// ---------------- phase 3: LayerNorm (in-place on out) ----------------
__global__ __launch_bounds__(256) void ln_rows(
    float* __restrict__ io,
    const float* __restrict__ gamma, const float* __restrict__ beta, int t0)
{
  int rid = blockIdx.x * 4 + (threadIdx.x >> 6);
  int l = threadIdx.x & 63;
  int b = rid >> 9, tl = rid & 511;
  float* p = io + ((size_t)b * T_ + t0 + tl) * U_ + l * 4;
  f32x4 v = *(const f32x4*)p;
  float s  = (v[0] + v[1]) + (v[2] + v[3]);
  float s2 = (v[0]*v[0] + v[1]*v[1]) + (v[2]*v[2] + v[3]*v[3]);
  #pragma unroll
  for (int off = 1; off <= 32; off <<= 1) {
    s  += __shfl_xor(s, off);
    s2 += __shfl_xor(s2, off);
  }
  float mu = s * (1.f / 256.f);
  float var = s2 * (1.f / 256.f) - mu * mu;
  float rs = rsqrtf(var + 1e-6f);
  f32x4 gm = *(const f32x4*)(gamma + l * 4);
  f32x4 bt = *(const f32x4*)(beta + l * 4);
  f32x4 o;
  o[0] = (v[0] - mu) * rs * gm[0] + bt[0];
  o[1] = (v[1] - mu) * rs * gm[1] + bt[1];
  o[2] = (v[2] - mu) * rs * gm[2] + bt[2];
  o[3] = (v[3] - mu) * rs * gm[3] + bt[3];
  *(f32x4*)p = o;
}

// ---------------- launcher ----------------
extern "C" void kernel_launch(void* const* d_in, const int* in_sizes, int n_in,
                              void* d_out, int out_size, void* d_ws, size_t ws_size,
                              hipStream_t stream) {
  const float* x     = (const float*)d_in[0];
  const float* kern  = (const float*)d_in[1];
  const float* rec   = (const float*)d_in[2];
  const float* bias  = (const float*)d_in[3];
  const float* gamma = (const float*)d_in[4];
  const float* beta  = (const float*)d_in[5];
  float* out = (float*)d_out;
  char* ws = (char*)d_ws;

  _Float16* xws = (_Float16*)(ws);                 // 8*512*12288 = 50,331,648 B
  _Float16* xhc = (_Float16*)(ws + 50331648);      // 16,777,216 B
  _Float16* kT  = (_Float16*)(ws + 67108864);      // 393,216 B
  _Float16* rT  = (_Float16*)(ws + 67502080);      // 393,216 B
  float*    hg  = (float*)   (ws + 67895296);      // 65,536 B

  conv_T<<<768, 256, 0, stream>>>(kern, kT);
  conv_T<<<768, 256, 0, stream>>>(rec,  rT);

  for (int c = 0; c < NCHUNK; ++c) {
    int t0 = c * TC;
    conv_x_chunk<<<4096, 256, 0, stream>>>(x, xhc, t0);
    gemm16<<<(B_ * TC / BM) * (NG / BN), 256, 0, stream>>>(xhc, kT, bias, xws);
    scan_mfma<<<G_, 512, 0, stream>>>(xws, rT, out, hg, t0);
    ln_rows<<<(B_ * TC) / 4, 256, 0, stream>>>(out, gamma, beta, t0);
  }
}

// Round 6
// 3048.048 us; speedup vs baseline: 1.0009x; 1.0009x over previous
//
#include <hip/hip_runtime.h>
#include <hip/hip_bf16.h>
#include <hip/hip_fp16.h>

using half4_t = __attribute__((ext_vector_type(4))) _Float16;
using half8_t = __attribute__((ext_vector_type(8))) _Float16;
using f32x4   = __attribute__((ext_vector_type(4))) float;

#define B_   64
#define T_   2048
#define D_   256
#define U_   256
#define NG   768
#define TC   512
#define NCHUNK (T_/TC)
#define NB   8
#define G_   8
#define PAGE_B 12288   // bytes per (g,t) xw page: 8*768*2

typedef const __attribute__((address_space(1))) void* gptr_t;
typedef __attribute__((address_space(3))) void* lptr_t;

__device__ __forceinline__ float rcpf(float x) { return __builtin_amdgcn_rcpf(x); }

// ---------------- conversions ----------------

__global__ void conv_x_chunk(const float* __restrict__ x, _Float16* __restrict__ xh, int t0) {
  size_t idx = ((size_t)blockIdx.x * 256 + threadIdx.x) * 8;
  int b   = (int)(idx >> 17);
  int rem = (int)(idx & 131071);
  const float4* p = (const float4*)(x + ((size_t)(b * T_ + t0)) * D_ + rem);
  float4 v0 = p[0], v1 = p[1];
  half8_t o;
  o[0] = (_Float16)v0.x; o[1] = (_Float16)v0.y; o[2] = (_Float16)v0.z; o[3] = (_Float16)v0.w;
  o[4] = (_Float16)v1.x; o[5] = (_Float16)v1.y; o[6] = (_Float16)v1.z; o[7] = (_Float16)v1.w;
  *(half8_t*)(xh + idx) = o;
}

// src [256][768] f32 -> dst [768][256] f16 (transpose + convert)
__global__ void conv_T(const float* __restrict__ src, _Float16* __restrict__ dst) {
  int idx = blockIdx.x * 256 + threadIdx.x;
  int d = idx / NG;
  int j = idx - d * NG;
  dst[j * 256 + d] = (_Float16)src[idx];
}

// ---------------- phase 1: xw = x @ kernel + bias -> scattered scan fragments ----------------
#define BM 128
#define BN 128

__global__ __launch_bounds__(256, 2) void gemm16(
    const _Float16* __restrict__ A,
    const _Float16* __restrict__ BT,
    const float* __restrict__ bias,
    _Float16* __restrict__ xwl)
{
  __shared__ alignas(16) _Float16 As[BM * 32];
  __shared__ alignas(16) _Float16 Bs[BN * 32];
  const int tid = threadIdx.x, l = tid & 63, w = tid >> 6;
  const int NT = NG / BN;
  const int mt = blockIdx.x / NT, nt = blockIdx.x % NT;
  const char* Ab = (const char*)A  + (size_t)mt * BM * 512;
  const char* Bb = (const char*)BT + (size_t)nt * BN * 512;
  const int wm = (w & 1) * 64, wn = (w >> 1) * 64;
  f32x4 acc[4][4] = {};

  for (int kt = 0; kt < 8; ++kt) {
    #pragma unroll
    for (int s = 0; s < 2; ++s) {
      int c = tid + s * 256;
      int row = c >> 2, gq = c & 3;
      int gs = gq ^ ((row >> 1) & 3);
      __builtin_amdgcn_global_load_lds(
        (gptr_t)(Ab + (size_t)row * 512 + kt * 64 + gs * 16),
        (lptr_t)((char*)As + c * 16), 16, 0, 0);
    }
    #pragma unroll
    for (int s = 0; s < 2; ++s) {
      int c = tid + s * 256;
      int row = c >> 2, gq = c & 3;
      int gs = gq ^ ((row >> 1) & 3);
      __builtin_amdgcn_global_load_lds(
        (gptr_t)(Bb + (size_t)row * 512 + kt * 64 + gs * 16),
        (lptr_t)((char*)Bs + c * 16), 16, 0, 0);
    }
    __syncthreads();

    half8_t av[4], bv[4];
    #pragma unroll
    for (int m = 0; m < 4; ++m) {
      int row = wm + m * 16 + (l & 15);
      int off = row * 64 + (((l >> 4) ^ ((row >> 1) & 3)) << 4);
      av[m] = *(const half8_t*)((const char*)As + off);
    }
    #pragma unroll
    for (int n = 0; n < 4; ++n) {
      int row = wn + n * 16 + (l & 15);
      int off = row * 64 + (((l >> 4) ^ ((row >> 1) & 3)) << 4);
      bv[n] = *(const half8_t*)((const char*)Bs + off);
    }
    #pragma unroll
    for (int m = 0; m < 4; ++m)
      #pragma unroll
      for (int n = 0; n < 4; ++n)
        acc[m][n] = __builtin_amdgcn_mfma_f32_16x16x32_f16(av[m], bv[n], acc[m][n], 0, 0, 0);
    __syncthreads();
  }

  // epilogue: scatter into scan fragment layout, bias added.
  int m0 = mt * BM, n0 = nt * BN;
  #pragma unroll
  for (int m = 0; m < 4; ++m) {
    #pragma unroll
    for (int n = 0; n < 4; ++n) {
      int c = n0 + wn + n * 16 + (l & 15);
      int gate = c >> 8, u = c & 255;
      int wv = u >> 5, tt2 = (u >> 4) & 1, hi2 = (u >> 2) & 3, q2 = u & 3;
      size_t coff = (size_t)wv * 768 + gate * 256 + tt2 * 128 + hi2 * 4 + q2;
      float bc = bias[c];
      #pragma unroll
      for (int q = 0; q < 4; ++q) {
        int arow = m0 + wm + m * 16 + ((l >> 4) * 4 + q);
        int b = arow >> 9, tloc = arow & 511;
        int gg = b >> 3, be2 = b & 7;
        xwl[(size_t)(gg * 512 + tloc) * 6144 + coff + be2 * 16] = (_Float16)(acc[m][n][q] + bc);
      }
    }
  }
}

// ---------------- phase 2: MFMA GRU scan, rec register-resident ----------------
#define DECLK(k) half8_t A0_##k, A1_##k, A2_##k, A3_##k, A4_##k, A5_##k;
#define LOADK(k) A0_##k = rp0[4*k]; A1_##k = rp1[4*k]; A2_##k = rp2[4*k]; \
                 A3_##k = rp3[4*k]; A4_##k = rp4[4*k]; A5_##k = rp5[4*k];
// Opaque pass-through: forbids rematerialization-by-reload, pins frags in VGPRs.
#define PINK(k) asm volatile("" : "+v"(A0_##k), "+v"(A1_##k), "+v"(A2_##k), \
                                  "+v"(A3_##k), "+v"(A4_##k), "+v"(A5_##k));
#define MSTEP(k) { half8_t Bf = *(const half8_t*)(hb + (bi << 9) + ((((k)*4 + hi) ^ (bi & 7)) << 4)); \
  a0 = __builtin_amdgcn_mfma_f32_16x16x32_f16(A0_##k, Bf, a0, 0, 0, 0); \
  a1 = __builtin_amdgcn_mfma_f32_16x16x32_f16(A1_##k, Bf, a1, 0, 0, 0); \
  a2 = __builtin_amdgcn_mfma_f32_16x16x32_f16(A2_##k, Bf, a2, 0, 0, 0); \
  a3 = __builtin_amdgcn_mfma_f32_16x16x32_f16(A3_##k, Bf, a3, 0, 0, 0); \
  a4 = __builtin_amdgcn_mfma_f32_16x16x32_f16(A4_##k, Bf, a4, 0, 0, 0); \
  a5 = __builtin_amdgcn_mfma_f32_16x16x32_f16(A5_##k, Bf, a5, 0, 0, 0); }

#define GSTEP(q, hrq) { \
      float sz = __shfl_up(a1[q], 8, 16); \
      float sr = __shfl_up(a3[q], 8, 16); \
      float sh = __shfl_up(a5[q], 8, 16); \
      float az = tte ? sz : a0[q]; \
      float ar = tte ? sr : a2[q]; \
      float ah = tte ? sh : a4[q]; \
      float zp  = az + (float)xz[q]; \
      float rp_ = ar + (float)xr[q]; \
      float hp_ = ah + (float)xh[q]; \
      float zz = rcpf(1.f + __expf(-zp)); \
      float rr = rcpf(1.f + __expf(-rp_)); \
      float y  = rr * (hp_ - hrq) + hrq; \
      float th = 2.f * rcpf(1.f + __expf(-2.f * y)) - 1.f; \
      hrq = zz * (hrq - th) + th; \
      hp[q] = (_Float16)hrq; ov[q] = hrq; }

__global__
__attribute__((amdgpu_flat_work_group_size(512, 512)))
__attribute__((amdgpu_waves_per_eu(2, 2)))
void scan_mfma(
    const _Float16* __restrict__ xws,
    const _Float16* __restrict__ rT,     // [768][256] f16
    float* __restrict__ out,             // [64][2048][256] f32 (pre-LN h written here)
    float* __restrict__ hg,              // [64][256] f32
    int t0)
{
  const int g = blockIdx.x, tid = threadIdx.x;
  const int w = tid >> 6, l = tid & 63, bi = l & 15, hi = l >> 4;
  const int be = bi & 7, tte = bi >> 3;
  const int u0e = 32 * w + tte * 16 + hi * 4;

  __shared__ alignas(16) _Float16 Hsw[2][16 * 256];   // 2 x 8 KB, granule-swizzled

  { half8_t z8 = {};
    *(half8_t*)((char*)Hsw + tid * 16) = z8;
    *(half8_t*)((char*)Hsw + 8192 + tid * 16) = z8; }

  const half8_t* rp0 = (const half8_t*)(rT + (size_t)((2*w + 0)*16 + bi) * 256 + hi * 8);
  const half8_t* rp1 = (const half8_t*)(rT + (size_t)((2*w + 1)*16 + bi) * 256 + hi * 8);
  const half8_t* rp2 = (const half8_t*)(rT + (size_t)((16 + 2*w)*16 + bi) * 256 + hi * 8);
  const half8_t* rp3 = (const half8_t*)(rT + (size_t)((17 + 2*w)*16 + bi) * 256 + hi * 8);
  const half8_t* rp4 = (const half8_t*)(rT + (size_t)((32 + 2*w)*16 + bi) * 256 + hi * 8);
  const half8_t* rp5 = (const half8_t*)(rT + (size_t)((33 + 2*w)*16 + bi) * 256 + hi * 8);

  DECLK(0) DECLK(1) DECLK(2) DECLK(3) DECLK(4) DECLK(5) DECLK(6) DECLK(7)
  LOADK(0) LOADK(1) LOADK(2) LOADK(3) LOADK(4) LOADK(5) LOADK(6) LOADK(7)
  PINK(0) PINK(1) PINK(2) PINK(3) PINK(4) PINK(5) PINK(6) PINK(7)

  float hr0, hr1, hr2, hr3;
  if (t0 == 0) { hr0 = hr1 = hr2 = hr3 = 0.f; }
  else { f32x4 hv = *(const f32x4*)(hg + (size_t)(g * 8 + be) * 256 + u0e);
         hr0 = hv[0]; hr1 = hv[1]; hr2 = hv[2]; hr3 = hv[3]; }

  const int gran0 = 4 * w + 2 * tte + (hi >> 1);
  const int hwoff = (be << 9) + ((gran0 ^ be) << 4) + ((hi & 1) << 3);

  __syncthreads();   // zero-init done
  { half4_t hp0;
    hp0[0] = (_Float16)hr0; hp0[1] = (_Float16)hr1;
    hp0[2] = (_Float16)hr2; hp0[3] = (_Float16)hr3;
    *(half4_t*)((char*)Hsw + hwoff) = hp0; }

  const char* xp = (const char*)xws + (size_t)g * TC * PAGE_B
                 + ((w * 768 + be * 16 + hi * 4) << 1) + (tte << 8);
  half4_t xz = *(const half4_t*)(xp);
  half4_t xr = *(const half4_t*)(xp + 512);
  half4_t xh = *(const half4_t*)(xp + 1024);

  float* outp = out + ((size_t)(g * 8 + be) * T_ + t0) * U_ + u0e;

  __syncthreads();   // h0 visible

  for (int t = 0; t < TC; ++t) {
    const char* hb = (const char*)Hsw + ((t & 1) << 13);
    f32x4 a0 = {}, a1 = {}, a2 = {}, a3 = {}, a4 = {}, a5 = {};
    MSTEP(0) MSTEP(1) MSTEP(2) MSTEP(3) MSTEP(4) MSTEP(5) MSTEP(6) MSTEP(7)

    half4_t hp; f32x4 ov;
    GSTEP(0, hr0) GSTEP(1, hr1) GSTEP(2, hr2) GSTEP(3, hr3)

    *(half4_t*)((char*)Hsw + (((t & 1) ^ 1) << 13) + hwoff) = hp;
    *(f32x4*)outp = ov;
    outp += U_;

    if (t + 1 < TC) {
      xp += PAGE_B;
      xz = *(const half4_t*)(xp);
      xr = *(const half4_t*)(xp + 512);
      xh = *(const half4_t*)(xp + 1024);
    }
    __syncthreads();
  }

  { f32x4 hv; hv[0] = hr0; hv[1] = hr1; hv[2] = hr2; hv[3] = hr3;
    *(f32x4*)(hg + (size_t)(g * 8 + be) * 256 + u0e) = hv; }
}

// ---------------- phase 3: LayerNorm (in-place on out) ----------------
__global__ __launch_bounds__(256) void ln_rows(
    float* __restrict__ io,
    const float* __restrict__ gamma, const float* __restrict__ beta, int t0)
{
  int rid = blockIdx.x * 4 + (threadIdx.x >> 6);
  int l = threadIdx.x & 63;
  int b = rid >> 9, tl = rid & 511;
  float* p = io + ((size_t)b * T_ + t0 + tl) * U_ + l * 4;
  f32x4 v = *(const f32x4*)p;
  float s  = (v[0] + v[1]) + (v[2] + v[3]);
  float s2 = (v[0]*v[0] + v[1]*v[1]) + (v[2]*v[2] + v[3]*v[3]);
  #pragma unroll
  for (int off = 1; off <= 32; off <<= 1) {
    s  += __shfl_xor(s, off);
    s2 += __shfl_xor(s2, off);
  }
  float mu = s * (1.f / 256.f);
  float var = s2 * (1.f / 256.f) - mu * mu;
  float rs = rsqrtf(var + 1e-6f);
  f32x4 gm = *(const f32x4*)(gamma + l * 4);
  f32x4 bt = *(const f32x4*)(beta + l * 4);
  f32x4 o;
  o[0] = (v[0] - mu) * rs * gm[0] + bt[0];
  o[1] = (v[1] - mu) * rs * gm[1] + bt[1];
  o[2] = (v[2] - mu) * rs * gm[2] + bt[2];
  o[3] = (v[3] - mu) * rs * gm[3] + bt[3];
  *(f32x4*)p = o;
}

// ---------------- launcher ----------------
extern "C" void kernel_launch(void* const* d_in, const int* in_sizes, int n_in,
                              void* d_out, int out_size, void* d_ws, size_t ws_size,
                              hipStream_t stream) {
  const float* x     = (const float*)d_in[0];
  const float* kern  = (const float*)d_in[1];
  const float* rec   = (const float*)d_in[2];
  const float* bias  = (const float*)d_in[3];
  const float* gamma = (const float*)d_in[4];
  const float* beta  = (const float*)d_in[5];
  float* out = (float*)d_out;
  char* ws = (char*)d_ws;

  _Float16* xws = (_Float16*)(ws);                 // 8*512*12288 = 50,331,648 B
  _Float16* xhc = (_Float16*)(ws + 50331648);      // 16,777,216 B
  _Float16* kT  = (_Float16*)(ws + 67108864);      // 393,216 B
  _Float16* rT  = (_Float16*)(ws + 67502080);      // 393,216 B
  float*    hg  = (float*)   (ws + 67895296);      // 65,536 B

  conv_T<<<768, 256, 0, stream>>>(kern, kT);
  conv_T<<<768, 256, 0, stream>>>(rec,  rT);

  for (int c = 0; c < NCHUNK; ++c) {
    int t0 = c * TC;
    conv_x_chunk<<<4096, 256, 0, stream>>>(x, xhc, t0);
    gemm16<<<(B_ * TC / BM) * (NG / BN), 256, 0, stream>>>(xhc, kT, bias, xws);
    scan_mfma<<<G_, 512, 0, stream>>>(xws, rT, out, hg, t0);
    ln_rows<<<(B_ * TC) / 4, 256, 0, stream>>>(out, gamma, beta, t0);
  }
}

// Round 8
// 1581.433 us; speedup vs baseline: 1.9292x; 1.9274x over previous
//
#include <hip/hip_runtime.h>
#include <hip/hip_bf16.h>
#include <hip/hip_fp16.h>

using half4_t = __attribute__((ext_vector_type(4))) _Float16;
using half8_t = __attribute__((ext_vector_type(8))) _Float16;
using f32x4   = __attribute__((ext_vector_type(4))) float;
using i32x4   = __attribute__((ext_vector_type(4))) int;

#define B_   64
#define T_   2048
#define D_   256
#define U_   256
#define NG   768
#define TC   512
#define NCHUNK (T_/TC)
#define GB   16      // scan blocks (4 batches each)

typedef const __attribute__((address_space(1))) void* gptr_t;
typedef __attribute__((address_space(3))) void* lptr_t;

__device__ __forceinline__ float rcpf(float x) { return __builtin_amdgcn_rcpf(x); }

// ---------------- conversions ----------------

__global__ void conv_x_chunk(const float* __restrict__ x, _Float16* __restrict__ xh, int t0) {
  size_t idx = ((size_t)blockIdx.x * 256 + threadIdx.x) * 8;
  int b   = (int)(idx >> 17);
  int rem = (int)(idx & 131071);
  const float4* p = (const float4*)(x + ((size_t)(b * T_ + t0)) * D_ + rem);
  float4 v0 = p[0], v1 = p[1];
  half8_t o;
  o[0] = (_Float16)v0.x; o[1] = (_Float16)v0.y; o[2] = (_Float16)v0.z; o[3] = (_Float16)v0.w;
  o[4] = (_Float16)v1.x; o[5] = (_Float16)v1.y; o[6] = (_Float16)v1.z; o[7] = (_Float16)v1.w;
  *(half8_t*)(xh + idx) = o;
}

// src [256][768] f32 -> dst [768][256] f16 (transpose + convert)  (for GEMM B)
__global__ void conv_T(const float* __restrict__ src, _Float16* __restrict__ dst) {
  int idx = blockIdx.x * 256 + threadIdx.x;
  int d = idx / NG;
  int j = idx - d * NG;
  dst[j * 256 + d] = (_Float16)src[idx];
}

// ---------------- rec -> i8 fragments ----------------

__global__ void init_scale(unsigned* s) { if (threadIdx.x == 0) *s = 0u; }

__global__ void absmax_rec(const float* __restrict__ rec, unsigned* __restrict__ s) {
  int i = (blockIdx.x * 256 + threadIdx.x) * 4;   // 192 blocks -> 196608 exactly
  float4 v = *(const float4*)(rec + i);
  float m = fmaxf(fmaxf(fabsf(v.x), fabsf(v.y)), fmaxf(fabsf(v.z), fabsf(v.w)));
  #pragma unroll
  for (int off = 32; off >= 1; off >>= 1) m = fmaxf(m, __shfl_xor(m, off));
  __shared__ float sm[4];
  int l = threadIdx.x & 63, wv = threadIdx.x >> 6;
  if (l == 0) sm[wv] = m;
  __syncthreads();
  if (threadIdx.x == 0) {
    m = fmaxf(fmaxf(sm[0], sm[1]), fmaxf(sm[2], sm[3]));
    atomicMax(s, __float_as_uint(m));
  }
}

// rec [256][768] f32 -> i8 A-fragment layout [48 mt][4 ks][64 lane][16B]
__global__ void conv_rec_i8(const float* __restrict__ rec, const unsigned* __restrict__ sc,
                            char* __restrict__ dst) {
  int idx = blockIdx.x * 256 + threadIdx.x;       // 768 blocks -> 196608
  int j = idx & 15, l = (idx >> 4) & 63, sl = idx >> 10;
  int mt = sl >> 2, ks = sl & 3, bi = l & 15, hi = l >> 4;
  float am = __uint_as_float(*sc) + 1e-30f;
  float s = 127.f / am;
  float v = rec[(size_t)(ks * 64 + hi * 16 + j) * NG + mt * 16 + bi] * s;
  int q = __float2int_rn(v);
  q = q > 127 ? 127 : (q < -127 ? -127 : q);
  dst[idx] = (char)q;
}

// ---------------- phase 1: xw = x @ kernel + bias -> per-lane scan layout ----------------
#define BM 128
#define BN 128

__global__ __launch_bounds__(256, 2) void gemm16(
    const _Float16* __restrict__ A,
    const _Float16* __restrict__ BT,
    const float* __restrict__ bias,
    _Float16* __restrict__ xwl)      // [16][512][3][1024]
{
  __shared__ alignas(16) _Float16 As[BM * 32];
  __shared__ alignas(16) _Float16 Bs[BN * 32];
  const int tid = threadIdx.x, l = tid & 63, w = tid >> 6;
  const int NT = NG / BN;
  const int mt = blockIdx.x / NT, nt = blockIdx.x % NT;
  const char* Ab = (const char*)A  + (size_t)mt * BM * 512;
  const char* Bb = (const char*)BT + (size_t)nt * BN * 512;
  const int wm = (w & 1) * 64, wn = (w >> 1) * 64;
  f32x4 acc[4][4] = {};

  for (int kt = 0; kt < 8; ++kt) {
    #pragma unroll
    for (int s = 0; s < 2; ++s) {
      int c = tid + s * 256;
      int row = c >> 2, gq = c & 3;
      int gs = gq ^ ((row >> 1) & 3);
      __builtin_amdgcn_global_load_lds(
        (gptr_t)(Ab + (size_t)row * 512 + kt * 64 + gs * 16),
        (lptr_t)((char*)As + c * 16), 16, 0, 0);
    }
    #pragma unroll
    for (int s = 0; s < 2; ++s) {
      int c = tid + s * 256;
      int row = c >> 2, gq = c & 3;
      int gs = gq ^ ((row >> 1) & 3);
      __builtin_amdgcn_global_load_lds(
        (gptr_t)(Bb + (size_t)row * 512 + kt * 64 + gs * 16),
        (lptr_t)((char*)Bs + c * 16), 16, 0, 0);
    }
    __syncthreads();

    half8_t av[4], bv[4];
    #pragma unroll
    for (int m = 0; m < 4; ++m) {
      int row = wm + m * 16 + (l & 15);
      int off = row * 64 + (((l >> 4) ^ ((row >> 1) & 3)) << 4);
      av[m] = *(const half8_t*)((const char*)As + off);
    }
    #pragma unroll
    for (int n = 0; n < 4; ++n) {
      int row = wn + n * 16 + (l & 15);
      int off = row * 64 + (((l >> 4) ^ ((row >> 1) & 3)) << 4);
      bv[n] = *(const half8_t*)((const char*)Bs + off);
    }
    #pragma unroll
    for (int m = 0; m < 4; ++m)
      #pragma unroll
      for (int n = 0; n < 4; ++n)
        acc[m][n] = __builtin_amdgcn_mfma_f32_16x16x32_f16(av[m], bv[n], acc[m][n], 0, 0, 0);
    __syncthreads();
  }

  // epilogue: scatter to [g][tloc][gate][wv*64 + bc + qq*4 + hi*16], bias added
  int m0 = mt * BM, n0 = nt * BN;
  #pragma unroll
  for (int m = 0; m < 4; ++m) {
    #pragma unroll
    for (int n = 0; n < 4; ++n) {
      int c = n0 + wn + n * 16 + (l & 15);
      int gate = c >> 8, uu = c & 255;
      int wv = uu >> 4, hq = (uu >> 2) & 3, qv = uu & 3;
      int lane_tid = wv * 64 + (qv << 2) + (hq << 4);
      float bc = bias[c];
      #pragma unroll
      for (int q = 0; q < 4; ++q) {
        int arow = m0 + wm + m * 16 + ((l >> 4) * 4 + q);
        int b = arow >> 9, tloc = arow & 511;
        int g = b >> 2, bidx = b & 3;
        size_t dst = ((size_t)(g * 512 + tloc) * 3 + gate) * 1024 + lane_tid + bidx;
        xwl[dst] = (_Float16)(acc[m][n][q] + bc);
      }
    }
  }
}

// ---------------- phase 2: i8 MFMA GRU scan ----------------
// 16 blocks x 1024 thr (16 waves). Block g: batches 4g..4g+3.
// Wave w owns M-tiles {w, 16+w, 32+w} (z,r,hh for u-block w), 4 k-slices.
// Lane (bi,hi): bc=bi&3 (batch), qq=bi>>2 (owned q) -> exactly 1 gate-eval/lane.

__global__ __launch_bounds__(1024) void scan_i8(
    const char* __restrict__ rq,        // [48][4][64][16] i8
    const _Float16* __restrict__ xws,   // [16][512][3][1024]
    const unsigned* __restrict__ sc,
    float* __restrict__ out,            // [64][2048][256] f32 (pre-LN h)
    float* __restrict__ hg,             // [64][256] f32
    int t0)
{
  const int g = blockIdx.x, tid = threadIdx.x;
  const int w = tid >> 6, l = tid & 63, bi = l & 15, hi = l >> 4;
  const int bc = bi & 3, qq = bi >> 2;
  const int u = w * 16 + hi * 4 + qq;

  __shared__ alignas(16) char Hq[2][1024];

  // A-frags: 12 named i32x4 (48 VGPR)
  const i32x4* rp = (const i32x4*)rq;
#define FR(mt, ks) rp[((mt) * 4 + (ks)) * 64 + l]
  i32x4 Az0 = FR(w, 0),      Az1 = FR(w, 1),      Az2 = FR(w, 2),      Az3 = FR(w, 3);
  i32x4 Ar0 = FR(16 + w, 0), Ar1 = FR(16 + w, 1), Ar2 = FR(16 + w, 2), Ar3 = FR(16 + w, 3);
  i32x4 Ah0 = FR(32 + w, 0), Ah1 = FR(32 + w, 1), Ah2 = FR(32 + w, 2), Ah3 = FR(32 + w, 3);
#undef FR
  asm volatile("" : "+v"(Az0), "+v"(Az1), "+v"(Az2), "+v"(Az3),
                    "+v"(Ar0), "+v"(Ar1), "+v"(Ar2), "+v"(Ar3),
                    "+v"(Ah0), "+v"(Ah1), "+v"(Ah2), "+v"(Ah3));

  const float dq = (__uint_as_float(*sc) + 1e-30f) / (127.f * 127.f);

  float h = (t0 == 0) ? 0.f : hg[(size_t)(g * 4 + bc) * 256 + u];

  // H byte addr: row bc (256B), granule (u>>4 = w) XOR-swizzled by bc
  const int hwa = bc * 256 + ((w ^ bc) << 4) + hi * 4 + qq;
  { int q8 = __float2int_rn(h * 127.f); Hq[0][hwa] = (char)q8; }

  const _Float16* xp = xws + (size_t)g * 512 * 3072 + tid;
  float* outp = out + ((size_t)(g * 4 + bc) * T_ + t0) * U_ + u;

  _Float16 nz = xp[0], nr = xp[1024], nh = xp[2048];
  __syncthreads();

  for (int t = 0; t < TC; ++t) {
    float xzf = (float)nz, xrf = (float)nr, xhf = (float)nh;
    {
      int tn = (t + 1 < TC) ? (t + 1) : t;
      const _Float16* xq = xp + (size_t)tn * 3072;
      nz = xq[0]; nr = xq[1024]; nh = xq[2048];
    }

    const char* hb = &Hq[t & 1][0];
    i32x4 az = {}, ar = {}, ah = {};
#define BADDR(ks) (bc * 256 + ((((ks) * 4 + hi) ^ bc) << 4))
    { i32x4 Bf;
      Bf = *(const i32x4*)(hb + BADDR(0));
      az = __builtin_amdgcn_mfma_i32_16x16x64_i8(Az0, Bf, az, 0, 0, 0);
      ar = __builtin_amdgcn_mfma_i32_16x16x64_i8(Ar0, Bf, ar, 0, 0, 0);
      ah = __builtin_amdgcn_mfma_i32_16x16x64_i8(Ah0, Bf, ah, 0, 0, 0);
      Bf = *(const i32x4*)(hb + BADDR(1));
      az = __builtin_amdgcn_mfma_i32_16x16x64_i8(Az1, Bf, az, 0, 0, 0);
      ar = __builtin_amdgcn_mfma_i32_16x16x64_i8(Ar1, Bf, ar, 0, 0, 0);
      ah = __builtin_amdgcn_mfma_i32_16x16x64_i8(Ah1, Bf, ah, 0, 0, 0);
      Bf = *(const i32x4*)(hb + BADDR(2));
      az = __builtin_amdgcn_mfma_i32_16x16x64_i8(Az2, Bf, az, 0, 0, 0);
      ar = __builtin_amdgcn_mfma_i32_16x16x64_i8(Ar2, Bf, ar, 0, 0, 0);
      ah = __builtin_amdgcn_mfma_i32_16x16x64_i8(Ah2, Bf, ah, 0, 0, 0);
      Bf = *(const i32x4*)(hb + BADDR(3));
      az = __builtin_amdgcn_mfma_i32_16x16x64_i8(Az3, Bf, az, 0, 0, 0);
      ar = __builtin_amdgcn_mfma_i32_16x16x64_i8(Ar3, Bf, ar, 0, 0, 0);
      ah = __builtin_amdgcn_mfma_i32_16x16x64_i8(Ah3, Bf, ah, 0, 0, 0);
    }
#undef BADDR

    // select this lane's q component (constant indices -> cndmask)
#define SEL4(a) ((qq & 2) ? ((qq & 1) ? (a)[3] : (a)[2]) : ((qq & 1) ? (a)[1] : (a)[0]))
    float pz = (float)SEL4(az) * dq + xzf;
    float pr = (float)SEL4(ar) * dq + xrf;
    float ph = (float)SEL4(ah) * dq + xhf;
#undef SEL4
    float z  = rcpf(1.f + __expf(-pz));
    float r  = rcpf(1.f + __expf(-pr));
    float y  = r * (ph - h) + h;
    float th = 2.f * rcpf(1.f + __expf(-2.f * y)) - 1.f;
    h = z * (h - th) + th;

    outp[(size_t)t * U_] = h;
    int q8 = __float2int_rn(h * 127.f);
    Hq[(t & 1) ^ 1][hwa] = (char)q8;
    __syncthreads();
  }

  hg[(size_t)(g * 4 + bc) * 256 + u] = h;
}

// ---------------- phase 3: LayerNorm (in-place on out) ----------------
__global__ __launch_bounds__(256) void ln_rows(
    float* __restrict__ io,
    const float* __restrict__ gamma, const float* __restrict__ beta, int t0)
{
  int rid = blockIdx.x * 4 + (threadIdx.x >> 6);
  int l = threadIdx.x & 63;
  int b = rid >> 9, tl = rid & 511;
  float* p = io + ((size_t)b * T_ + t0 + tl) * U_ + l * 4;
  f32x4 v = *(const f32x4*)p;
  float s  = (v[0] + v[1]) + (v[2] + v[3]);
  float s2 = (v[0]*v[0] + v[1]*v[1]) + (v[2]*v[2] + v[3]*v[3]);
  #pragma unroll
  for (int off = 1; off <= 32; off <<= 1) {
    s  += __shfl_xor(s, off);
    s2 += __shfl_xor(s2, off);
  }
  float mu = s * (1.f / 256.f);
  float var = s2 * (1.f / 256.f) - mu * mu;
  float rs = rsqrtf(var + 1e-6f);
  f32x4 gm = *(const f32x4*)(gamma + l * 4);
  f32x4 bt = *(const f32x4*)(beta + l * 4);
  f32x4 o;
  o[0] = (v[0] - mu) * rs * gm[0] + bt[0];
  o[1] = (v[1] - mu) * rs * gm[1] + bt[1];
  o[2] = (v[2] - mu) * rs * gm[2] + bt[2];
  o[3] = (v[3] - mu) * rs * gm[3] + bt[3];
  *(f32x4*)p = o;
}

// ---------------- launcher ----------------
extern "C" void kernel_launch(void* const* d_in, const int* in_sizes, int n_in,
                              void* d_out, int out_size, void* d_ws, size_t ws_size,
                              hipStream_t stream) {
  const float* x     = (const float*)d_in[0];
  const float* kern  = (const float*)d_in[1];
  const float* rec   = (const float*)d_in[2];
  const float* bias  = (const float*)d_in[3];
  const float* gamma = (const float*)d_in[4];
  const float* beta  = (const float*)d_in[5];
  float* out = (float*)d_out;
  char* ws = (char*)d_ws;

  _Float16* xws = (_Float16*)(ws);                 // 16*512*3*1024*2 = 50,331,648 B
  _Float16* xhc = (_Float16*)(ws + 50331648);      // 16,777,216 B
  _Float16* kT  = (_Float16*)(ws + 67108864);      // 393,216 B
  char*     rq  = (char*)    (ws + 67502080);      // 196,608 B
  unsigned* sc  = (unsigned*)(ws + 67698688);      // 4 B (pad to 32)
  float*    hg  = (float*)   (ws + 67698720);      // 65,536 B

  init_scale<<<1, 64, 0, stream>>>(sc);
  absmax_rec<<<192, 256, 0, stream>>>(rec, sc);
  conv_T<<<768, 256, 0, stream>>>(kern, kT);
  conv_rec_i8<<<768, 256, 0, stream>>>(rec, sc, rq);

  for (int c = 0; c < NCHUNK; ++c) {
    int t0 = c * TC;
    conv_x_chunk<<<4096, 256, 0, stream>>>(x, xhc, t0);
    gemm16<<<(B_ * TC / BM) * (NG / BN), 256, 0, stream>>>(xhc, kT, bias, xws);
    scan_i8<<<GB, 1024, 0, stream>>>(rq, xws, sc, out, hg, t0);
    ln_rows<<<(B_ * TC) / 4, 256, 0, stream>>>(out, gamma, beta, t0);
  }
}

// Round 9
// 1465.969 us; speedup vs baseline: 2.0811x; 1.0788x over previous
//
#include <hip/hip_runtime.h>
#include <hip/hip_bf16.h>
#include <hip/hip_fp16.h>

using half2_t = __attribute__((ext_vector_type(2))) _Float16;
using half8_t = __attribute__((ext_vector_type(8))) _Float16;
using f32x4   = __attribute__((ext_vector_type(4))) float;
using i32x4   = __attribute__((ext_vector_type(4))) int;

#define B_   64
#define T_   2048
#define D_   256
#define U_   256
#define NG   768
#define TC   512
#define NCHUNK (T_/TC)
#define GB_SCAN 16     // scan blocks (4 batches each)
#define GB_GEMM 1536   // one 128x128 tile each
#define GB_LN   2048   // 16 rows each

typedef const __attribute__((address_space(1))) void* gptr_t;
typedef __attribute__((address_space(3))) void* lptr_t;

__device__ __forceinline__ float rcpf(float x) { return __builtin_amdgcn_rcpf(x); }

// ---------------- prep kernels ----------------

__global__ void conv_x_chunk(const float* __restrict__ x, _Float16* __restrict__ xh, int t0) {
  size_t idx = ((size_t)blockIdx.x * 256 + threadIdx.x) * 8;
  int b   = (int)(idx >> 17);
  int rem = (int)(idx & 131071);
  const float4* p = (const float4*)(x + ((size_t)(b * T_ + t0)) * D_ + rem);
  float4 v0 = p[0], v1 = p[1];
  half8_t o;
  o[0] = (_Float16)v0.x; o[1] = (_Float16)v0.y; o[2] = (_Float16)v0.z; o[3] = (_Float16)v0.w;
  o[4] = (_Float16)v1.x; o[5] = (_Float16)v1.y; o[6] = (_Float16)v1.z; o[7] = (_Float16)v1.w;
  *(half8_t*)(xh + idx) = o;
}

__global__ void conv_T(const float* __restrict__ src, _Float16* __restrict__ dst) {
  int idx = blockIdx.x * 256 + threadIdx.x;
  int d = idx / NG;
  int j = idx - d * NG;
  dst[j * 256 + d] = (_Float16)src[idx];
}

__global__ void init_scale(unsigned* s) { if (threadIdx.x == 0) *s = 0u; }

__global__ void absmax_rec(const float* __restrict__ rec, unsigned* __restrict__ s) {
  int i = (blockIdx.x * 256 + threadIdx.x) * 4;
  float4 v = *(const float4*)(rec + i);
  float m = fmaxf(fmaxf(fabsf(v.x), fabsf(v.y)), fmaxf(fabsf(v.z), fabsf(v.w)));
  #pragma unroll
  for (int off = 32; off >= 1; off >>= 1) m = fmaxf(m, __shfl_xor(m, off));
  __shared__ float sm[4];
  int l = threadIdx.x & 63, wv = threadIdx.x >> 6;
  if (l == 0) sm[wv] = m;
  __syncthreads();
  if (threadIdx.x == 0) {
    m = fmaxf(fmaxf(sm[0], sm[1]), fmaxf(sm[2], sm[3]));
    atomicMax(s, __float_as_uint(m));
  }
}

// rec [256][768] f32 -> i8 A-fragment layout [48 mt][4 ks][64 lane][16B]
__global__ void conv_rec_i8(const float* __restrict__ rec, const unsigned* __restrict__ sc,
                            char* __restrict__ dst) {
  int idx = blockIdx.x * 256 + threadIdx.x;
  int j = idx & 15, l = (idx >> 4) & 63, sl = idx >> 10;
  int mt = sl >> 2, ks = sl & 3, bi = l & 15, hi = l >> 4;
  float am = __uint_as_float(*sc) + 1e-30f;
  float s = 127.f / am;
  float v = rec[(size_t)(ks * 64 + hi * 16 + j) * NG + mt * 16 + bi] * s;
  int q = __float2int_rn(v);
  q = q > 127 ? 127 : (q < -127 ? -127 : q);
  dst[idx] = (char)q;
}

// ---------------- mega kernel: [scan | gemm | ln] by blockIdx range ----------------
// xws page layout per (g,t): 3072 f16 = 6144 B: [0,4096)B zr pairs (lane*4B), [4096,6144)B h (lane*2B)

__global__ __launch_bounds__(1024) void mega(
    // scan section
    const char* __restrict__ rq,        // [48][4][64][16] i8
    const _Float16* __restrict__ xwsS,  // scan input pages
    const unsigned* __restrict__ sc,
    float* __restrict__ out,
    float* __restrict__ hg,
    int scanT0,
    // gemm section
    const _Float16* __restrict__ xhc,   // [B][TC][256] f16
    const _Float16* __restrict__ kT,    // [768][256] f16
    const float* __restrict__ bias,
    _Float16* __restrict__ xwsG,        // gemm output pages
    // ln section
    const float* __restrict__ gamma,
    const float* __restrict__ beta,
    int lnT0,
    int nScan, int nGemm)
{
  __shared__ union UU {
    struct { char Hq[2][1024]; } s;
    struct { alignas(16) _Float16 As[128 * 32]; alignas(16) _Float16 Bs[128 * 32]; } g;
  } U;

  int bid = blockIdx.x;
  const int tid = threadIdx.x;

  // ================= SCAN =================
  if (bid < nScan) {
    const int g = bid;
    const int w = tid >> 6, l = tid & 63, bi = l & 15, hi = l >> 4;
    const int bc = bi & 3, qq = bi >> 2;
    const int u = w * 16 + hi * 4 + qq;

    // A-frags: 12 named i32x4 (48 VGPR)
    const i32x4* rp = (const i32x4*)rq;
#define FR(mt, ks) rp[((mt) * 4 + (ks)) * 64 + l]
    i32x4 Az0 = FR(w, 0),      Az1 = FR(w, 1),      Az2 = FR(w, 2),      Az3 = FR(w, 3);
    i32x4 Ar0 = FR(16 + w, 0), Ar1 = FR(16 + w, 1), Ar2 = FR(16 + w, 2), Ar3 = FR(16 + w, 3);
    i32x4 Ah0 = FR(32 + w, 0), Ah1 = FR(32 + w, 1), Ah2 = FR(32 + w, 2), Ah3 = FR(32 + w, 3);
#undef FR
    asm volatile("" : "+v"(Az0), "+v"(Az1), "+v"(Az2), "+v"(Az3),
                      "+v"(Ar0), "+v"(Ar1), "+v"(Ar2), "+v"(Ar3),
                      "+v"(Ah0), "+v"(Ah1), "+v"(Ah2), "+v"(Ah3));

    const float dq = (__uint_as_float(*sc) + 1e-30f) / (127.f * 127.f);

    float h = (scanT0 == 0) ? 0.f : hg[(size_t)(g * 4 + bc) * 256 + u];

    const int hwa = bc * 256 + ((w ^ bc) << 4) + hi * 4 + qq;
    { int q8 = __float2int_rn(h * 127.f); U.s.Hq[0][hwa] = (char)q8; }

    const char* xpg = (const char*)xwsS + (size_t)g * TC * 6144;
    float* outp = out + ((size_t)(g * 4 + bc) * T_ + scanT0) * U_ + u;

    unsigned nzr = *(const unsigned*)(xpg + tid * 4);
    _Float16 nh2 = *(const _Float16*)(xpg + 4096 + tid * 2);
    __syncthreads();

    for (int t = 0; t < TC; ++t) {
      half2_t zrp = __builtin_bit_cast(half2_t, nzr);
      float xzf = (float)zrp[0], xrf = (float)zrp[1], xhf = (float)nh2;
      {
        int tn = (t + 1 < TC) ? (t + 1) : t;
        nzr = *(const unsigned*)(xpg + (size_t)tn * 6144 + tid * 4);
        nh2 = *(const _Float16*)(xpg + (size_t)tn * 6144 + 4096 + tid * 2);
      }

      const char* hb = &U.s.Hq[t & 1][0];
      i32x4 az = {}, ar = {}, ah = {};
#define BADDR(ks) (bc * 256 + ((((ks) * 4 + hi) ^ bc) << 4))
      { i32x4 Bf;
        Bf = *(const i32x4*)(hb + BADDR(0));
        az = __builtin_amdgcn_mfma_i32_16x16x64_i8(Az0, Bf, az, 0, 0, 0);
        ar = __builtin_amdgcn_mfma_i32_16x16x64_i8(Ar0, Bf, ar, 0, 0, 0);
        ah = __builtin_amdgcn_mfma_i32_16x16x64_i8(Ah0, Bf, ah, 0, 0, 0);
        Bf = *(const i32x4*)(hb + BADDR(1));
        az = __builtin_amdgcn_mfma_i32_16x16x64_i8(Az1, Bf, az, 0, 0, 0);
        ar = __builtin_amdgcn_mfma_i32_16x16x64_i8(Ar1, Bf, ar, 0, 0, 0);
        ah = __builtin_amdgcn_mfma_i32_16x16x64_i8(Ah1, Bf, ah, 0, 0, 0);
        Bf = *(const i32x4*)(hb + BADDR(2));
        az = __builtin_amdgcn_mfma_i32_16x16x64_i8(Az2, Bf, az, 0, 0, 0);
        ar = __builtin_amdgcn_mfma_i32_16x16x64_i8(Ar2, Bf, ar, 0, 0, 0);
        ah = __builtin_amdgcn_mfma_i32_16x16x64_i8(Ah2, Bf, ah, 0, 0, 0);
        Bf = *(const i32x4*)(hb + BADDR(3));
        az = __builtin_amdgcn_mfma_i32_16x16x64_i8(Az3, Bf, az, 0, 0, 0);
        ar = __builtin_amdgcn_mfma_i32_16x16x64_i8(Ar3, Bf, ar, 0, 0, 0);
        ah = __builtin_amdgcn_mfma_i32_16x16x64_i8(Ah3, Bf, ah, 0, 0, 0);
      }
#undef BADDR

#define SEL4(a) ((qq & 2) ? ((qq & 1) ? (a)[3] : (a)[2]) : ((qq & 1) ? (a)[1] : (a)[0]))
      float pz = (float)SEL4(az) * dq + xzf;
      float pr = (float)SEL4(ar) * dq + xrf;
      float ph = (float)SEL4(ah) * dq + xhf;
#undef SEL4
      float z  = rcpf(1.f + __expf(-pz));
      float r  = rcpf(1.f + __expf(-pr));
      float y  = r * (ph - h) + h;
      float th = 2.f * rcpf(1.f + __expf(-2.f * y)) - 1.f;
      h = z * (h - th) + th;

      outp[(size_t)t * U_] = h;
      int q8 = __float2int_rn(h * 127.f);
      U.s.Hq[(t & 1) ^ 1][hwa] = (char)q8;
      __syncthreads();
    }

    hg[(size_t)(g * 4 + bc) * 256 + u] = h;
    return;
  }
  bid -= nScan;

  // ================= GEMM =================
  if (bid < nGemm) {
    const int tile = bid;
    const int mt = tile / 6, nt = tile % 6;
    const int w = tid >> 6, l = tid & 63;
    const int wm = (w & 3) * 32, wn = (w >> 2) * 32;
    const char* Ab = (const char*)xhc + (size_t)mt * 128 * 512;
    const char* Bb = (const char*)kT  + (size_t)nt * 128 * 512;
    f32x4 acc[2][2] = {};

    // staging addresses: thread -> one 16B chunk (A: tid<512, B: tid>=512)
    const bool isA = tid < 512;
    const int cc = isA ? tid : tid - 512;
    const int srow = cc >> 2, sgq = cc & 3;
    const int sgs = sgq ^ ((srow >> 1) & 3);
    const char* sb = isA ? Ab : Bb;
    char* ldsb = (char*)(isA ? U.g.As : U.g.Bs) + cc * 16;

    for (int kt = 0; kt < 8; ++kt) {
      __builtin_amdgcn_global_load_lds(
        (gptr_t)(sb + (size_t)srow * 512 + kt * 64 + sgs * 16),
        (lptr_t)ldsb, 16, 0, 0);
      __syncthreads();

      half8_t av[2], bv[2];
      #pragma unroll
      for (int mi = 0; mi < 2; ++mi) {
        int row = wm + mi * 16 + (l & 15);
        int off = row * 64 + (((l >> 4) ^ ((row >> 1) & 3)) << 4);
        av[mi] = *(const half8_t*)((const char*)U.g.As + off);
      }
      #pragma unroll
      for (int ni = 0; ni < 2; ++ni) {
        int row = wn + ni * 16 + (l & 15);
        int off = row * 64 + (((l >> 4) ^ ((row >> 1) & 3)) << 4);
        bv[ni] = *(const half8_t*)((const char*)U.g.Bs + off);
      }
      #pragma unroll
      for (int mi = 0; mi < 2; ++mi)
        #pragma unroll
        for (int ni = 0; ni < 2; ++ni)
          acc[mi][ni] = __builtin_amdgcn_mfma_f32_16x16x32_f16(av[mi], bv[ni], acc[mi][ni], 0, 0, 0);
      __syncthreads();
    }

    // epilogue: scatter to scan page layout with bias add
    #pragma unroll
    for (int mi = 0; mi < 2; ++mi) {
      #pragma unroll
      for (int ni = 0; ni < 2; ++ni) {
        int c = nt * 128 + wn + ni * 16 + (l & 15);
        int cgate = c >> 8, uu = c & 255;
        int wv = uu >> 4, hq = (uu >> 2) & 3, qv = uu & 3;
        int lane_tid = wv * 64 + (qv << 2) + (hq << 4);
        float bc = bias[c];
        #pragma unroll
        for (int q = 0; q < 4; ++q) {
          int arow = mt * 128 + wm + mi * 16 + ((l >> 4) * 4 + q);
          int b = arow >> 9, tloc = arow & 511;
          int g = b >> 2, bidx = b & 3;
          int lane = lane_tid + bidx;
          size_t page = (size_t)(g * 512 + tloc) * 3072;
          size_t dst = (cgate < 2) ? (page + (size_t)lane * 2 + cgate)
                                   : (page + 2048 + lane);
          xwsG[dst] = (_Float16)(acc[mi][ni][q] + bc);
        }
      }
    }
    return;
  }
  bid -= nGemm;

  // ================= LN (in-place on out) =================
  {
    int rid = bid * 16 + (tid >> 6);
    int l = tid & 63;
    int b = rid >> 9, tl = rid & 511;
    float* p = out + ((size_t)b * T_ + lnT0 + tl) * U_ + l * 4;
    f32x4 v = *(const f32x4*)p;
    float s  = (v[0] + v[1]) + (v[2] + v[3]);
    float s2 = (v[0]*v[0] + v[1]*v[1]) + (v[2]*v[2] + v[3]*v[3]);
    #pragma unroll
    for (int off = 1; off <= 32; off <<= 1) {
      s  += __shfl_xor(s, off);
      s2 += __shfl_xor(s2, off);
    }
    float mu = s * (1.f / 256.f);
    float var = s2 * (1.f / 256.f) - mu * mu;
    float rs = rsqrtf(var + 1e-6f);
    f32x4 gm = *(const f32x4*)(gamma + l * 4);
    f32x4 bt = *(const f32x4*)(beta + l * 4);
    f32x4 o;
    o[0] = (v[0] - mu) * rs * gm[0] + bt[0];
    o[1] = (v[1] - mu) * rs * gm[1] + bt[1];
    o[2] = (v[2] - mu) * rs * gm[2] + bt[2];
    o[3] = (v[3] - mu) * rs * gm[3] + bt[3];
    *(f32x4*)p = o;
  }
}

// ---------------- launcher ----------------
extern "C" void kernel_launch(void* const* d_in, const int* in_sizes, int n_in,
                              void* d_out, int out_size, void* d_ws, size_t ws_size,
                              hipStream_t stream) {
  const float* x     = (const float*)d_in[0];
  const float* kern  = (const float*)d_in[1];
  const float* rec   = (const float*)d_in[2];
  const float* bias  = (const float*)d_in[3];
  const float* gamma = (const float*)d_in[4];
  const float* beta  = (const float*)d_in[5];
  float* out = (float*)d_out;
  char* ws = (char*)d_ws;

  const size_t XWS = 50331648;  // 16*512*3072*2
  const bool pipe = (ws_size >= 118096000ull);

  _Float16* xwsA = (_Float16*)ws;
  _Float16* xwsB = pipe ? (_Float16*)(ws + XWS) : xwsA;
  size_t o = pipe ? 2 * XWS : XWS;
  _Float16* xhc = (_Float16*)(ws + o);           o += 16777216;
  _Float16* kT  = (_Float16*)(ws + o);           o += 393216;
  char*     rq  = (char*)    (ws + o);           o += 196608;
  unsigned* sc  = (unsigned*)(ws + o);           o += 128;
  float*    hg  = (float*)   (ws + o);

  init_scale<<<1, 64, 0, stream>>>(sc);
  absmax_rec<<<192, 256, 0, stream>>>(rec, sc);
  conv_T<<<768, 256, 0, stream>>>(kern, kT);
  conv_rec_i8<<<768, 256, 0, stream>>>(rec, sc, rq);

  if (pipe) {
    _Float16* xb[2] = { xwsA, xwsB };
    conv_x_chunk<<<4096, 256, 0, stream>>>(x, xhc, 0);
    // gemm(0) alone
    mega<<<GB_GEMM, 1024, 0, stream>>>(rq, xwsA, sc, out, hg, 0,
                                       xhc, kT, bias, xwsA, gamma, beta, 0,
                                       0, GB_GEMM);
    conv_x_chunk<<<4096, 256, 0, stream>>>(x, xhc, TC);
    // scan0 + gemm1
    mega<<<GB_SCAN + GB_GEMM, 1024, 0, stream>>>(rq, xwsA, sc, out, hg, 0,
                                       xhc, kT, bias, xwsB, gamma, beta, 0,
                                       GB_SCAN, GB_GEMM);
    conv_x_chunk<<<4096, 256, 0, stream>>>(x, xhc, 2 * TC);
    // scan1 + gemm2 + ln0
    mega<<<GB_SCAN + GB_GEMM + GB_LN, 1024, 0, stream>>>(rq, xwsB, sc, out, hg, TC,
                                       xhc, kT, bias, xwsA, gamma, beta, 0,
                                       GB_SCAN, GB_GEMM);
    conv_x_chunk<<<4096, 256, 0, stream>>>(x, xhc, 3 * TC);
    // scan2 + gemm3 + ln1
    mega<<<GB_SCAN + GB_GEMM + GB_LN, 1024, 0, stream>>>(rq, xwsA, sc, out, hg, 2 * TC,
                                       xhc, kT, bias, xwsB, gamma, beta, TC,
                                       GB_SCAN, GB_GEMM);
    // scan3 + ln2
    mega<<<GB_SCAN + GB_LN, 1024, 0, stream>>>(rq, xwsB, sc, out, hg, 3 * TC,
                                       xhc, kT, bias, xwsA, gamma, beta, 2 * TC,
                                       GB_SCAN, 0);
    // ln3
    mega<<<GB_LN, 1024, 0, stream>>>(rq, xwsA, sc, out, hg, 0,
                                       xhc, kT, bias, xwsA, gamma, beta, 3 * TC,
                                       0, 0);
    (void)xb;
  } else {
    for (int c = 0; c < NCHUNK; ++c) {
      int t0 = c * TC;
      conv_x_chunk<<<4096, 256, 0, stream>>>(x, xhc, t0);
      mega<<<GB_GEMM, 1024, 0, stream>>>(rq, xwsA, sc, out, hg, t0,
                                         xhc, kT, bias, xwsA, gamma, beta, t0,
                                         0, GB_GEMM);
      mega<<<GB_SCAN, 1024, 0, stream>>>(rq, xwsA, sc, out, hg, t0,
                                         xhc, kT, bias, xwsA, gamma, beta, t0,
                                         GB_SCAN, 0);
      mega<<<GB_LN, 1024, 0, stream>>>(rq, xwsA, sc, out, hg, t0,
                                       xhc, kT, bias, xwsA, gamma, beta, t0,
                                       0, 0);
    }
  }
}